// Round 2
// baseline (47.235 us; speedup 1.0000x reference)
//
#include <hip/hip_runtime.h>

// GraphConvolution_relative: out = relu(einsum('sn,sd->nd', diag, w))
// diag[s,i] = sum_{e: rows[s,e]==i} vals[s,e] * |x[r,c] + x[c,r]|
//
// Phase 1: zero R*S*N fp32 accumulators in d_ws (replicated to cut atomic contention)
// Phase 2: edge scatter, 4 edges/thread (int4/float4 streaming, 8 in-flight gathers)
// Phase 3: epilogue sums replicas, outer-product with w, relu

#define N_NODES 8192
#define S_SUP   2
#define E_EDGES 262144   // 2^18
#define D_OUT   128
#define NREP    4        // diag replicas (power of 2)

__global__ __launch_bounds__(256)
void gc_edge4_kernel(const float* __restrict__ x,
                     const int4*  __restrict__ rows4,
                     const int4*  __restrict__ cols4,
                     const float4* __restrict__ vals4,
                     float*       __restrict__ diag,   // [NREP][S][N]
                     int rep_mask) {
    int t = blockIdx.x * blockDim.x + threadIdx.x;     // over S*E/4 = 131072
    if (t >= S_SUP * E_EDGES / 4) return;
    int4  r = rows4[t];
    int4  c = cols4[t];
    float4 v = vals4[t];
    int s = t >> 16;                                   // (4t)/E_EDGES

    // 8 independent gathers, all issued before any use
    float a0 = x[(r.x << 13) | c.x];
    float b0 = x[(c.x << 13) | r.x];
    float a1 = x[(r.y << 13) | c.y];
    float b1 = x[(c.y << 13) | r.y];
    float a2 = x[(r.z << 13) | c.z];
    float b2 = x[(c.z << 13) | r.z];
    float a3 = x[(r.w << 13) | c.w];
    float b3 = x[(c.w << 13) | r.w];

    float t0 = fabsf(a0 + b0) * v.x;
    float t1 = fabsf(a1 + b1) * v.y;
    float t2 = fabsf(a2 + b2) * v.z;
    float t3 = fabsf(a3 + b3) * v.w;

    float* base = diag + (((blockIdx.x & rep_mask) * S_SUP + s) << 13);
    atomicAdd(&base[r.x], t0);
    atomicAdd(&base[r.y], t1);
    atomicAdd(&base[r.z], t2);
    atomicAdd(&base[r.w], t3);
}

__global__ __launch_bounds__(256)
void gc_out_kernel(const float* __restrict__ diag,   // [nrep][S][N]
                   const float* __restrict__ w,
                   float*       __restrict__ out,
                   int nrep) {
    int idx = blockIdx.x * blockDim.x + threadIdx.x;   // over N*D/4
    int d4 = idx & (D_OUT / 4 - 1);                    // 0..31
    int n  = idx >> 5;
    if (n >= N_NODES) return;
    float d0 = 0.0f, d1 = 0.0f;
    for (int rp = 0; rp < nrep; ++rp) {
        d0 += diag[((rp * S_SUP + 0) << 13) + n];
        d1 += diag[((rp * S_SUP + 1) << 13) + n];
    }
    const float4 w0 = ((const float4*)w)[d4];               // w[0][d..d+3]
    const float4 w1 = ((const float4*)w)[D_OUT / 4 + d4];   // w[1][d..d+3]
    float4 o;
    o.x = fmaxf(fmaf(d0, w0.x, d1 * w1.x), 0.0f);
    o.y = fmaxf(fmaf(d0, w0.y, d1 * w1.y), 0.0f);
    o.z = fmaxf(fmaf(d0, w0.z, d1 * w1.z), 0.0f);
    o.w = fmaxf(fmaf(d0, w0.w, d1 * w1.w), 0.0f);
    ((float4*)out)[idx] = o;
}

extern "C" void kernel_launch(void* const* d_in, const int* in_sizes, int n_in,
                              void* d_out, int out_size, void* d_ws, size_t ws_size,
                              hipStream_t stream) {
    const float* x    = (const float*)d_in[0];
    const int*   rows = (const int*)  d_in[1];
    const int*   cols = (const int*)  d_in[2];
    const float* vals = (const float*)d_in[3];
    const float* w    = (const float*)d_in[4];
    float* out  = (float*)d_out;
    float* diag = (float*)d_ws;

    // pick replica count that fits the workspace
    size_t per_rep = (size_t)S_SUP * N_NODES * sizeof(float);   // 64 KB
    int nrep = (ws_size >= NREP * per_rep) ? NREP : 1;
    int rep_mask = nrep - 1;

    hipMemsetAsync(diag, 0, (size_t)nrep * per_rep, stream);

    {
        int total = S_SUP * E_EDGES / 4;
        int block = 256;
        int grid  = (total + block - 1) / block;
        gc_edge4_kernel<<<grid, block, 0, stream>>>(
            x, (const int4*)rows, (const int4*)cols, (const float4*)vals,
            diag, rep_mask);
    }
    {
        int total = N_NODES * D_OUT / 4;
        int block = 256;
        int grid  = (total + block - 1) / block;
        gc_out_kernel<<<grid, block, 0, stream>>>(diag, w, out, nrep);
    }
}

// Round 3
// 42.854 us; speedup vs baseline: 1.1022x; 1.1022x over previous
//
#include <hip/hip_runtime.h>

// GraphConvolution_relative: out = relu(einsum('sn,sd->nd', diag, w))
// diag[s,i] = sum_{e: rows[s,e]==i} vals[s,e] * |x[r,c] + x[c,r]|
//
// Round 3: revert to round-1 structure (fastest so far); single new variable:
// nontemporal hint on the two random x-gathers (reuse ~1.28x, skip L2 alloc).

#define N_NODES 8192
#define S_SUP   2
#define E_EDGES 262144   // 2^18
#define D_OUT   128

__global__ __launch_bounds__(256)
void gc_edge_kernel(const float* __restrict__ x,
                    const int*   __restrict__ rows,
                    const int*   __restrict__ cols,
                    const float* __restrict__ vals,
                    float*       __restrict__ diag) {
    int idx = blockIdx.x * blockDim.x + threadIdx.x;
    if (idx >= S_SUP * E_EDGES) return;
    int s = idx >> 18;                 // idx / E_EDGES
    int r = rows[idx];
    int c = cols[idx];
    float v = vals[idx];
    float a = __builtin_nontemporal_load(&x[(r << 13) | c]);
    float b = __builtin_nontemporal_load(&x[(c << 13) | r]);
    float t = fabsf(a + b) * v;
    atomicAdd(&diag[(s << 13) + r], t);
}

__global__ __launch_bounds__(256)
void gc_out_kernel(const float* __restrict__ diag,
                   const float* __restrict__ w,
                   float*       __restrict__ out) {
    int idx = blockIdx.x * blockDim.x + threadIdx.x;   // over N*D/4
    int d4 = idx & (D_OUT / 4 - 1);                    // 0..31
    int n  = idx >> 5;
    if (n >= N_NODES) return;
    float d0 = diag[n];
    float d1 = diag[N_NODES + n];
    const float4 w0 = ((const float4*)w)[d4];               // w[0][d..d+3]
    const float4 w1 = ((const float4*)w)[D_OUT / 4 + d4];   // w[1][d..d+3]
    float4 o;
    o.x = fmaxf(fmaf(d0, w0.x, d1 * w1.x), 0.0f);
    o.y = fmaxf(fmaf(d0, w0.y, d1 * w1.y), 0.0f);
    o.z = fmaxf(fmaf(d0, w0.z, d1 * w1.z), 0.0f);
    o.w = fmaxf(fmaf(d0, w0.w, d1 * w1.w), 0.0f);
    ((float4*)out)[idx] = o;
}

extern "C" void kernel_launch(void* const* d_in, const int* in_sizes, int n_in,
                              void* d_out, int out_size, void* d_ws, size_t ws_size,
                              hipStream_t stream) {
    const float* x    = (const float*)d_in[0];
    const int*   rows = (const int*)  d_in[1];
    const int*   cols = (const int*)  d_in[2];
    const float* vals = (const float*)d_in[3];
    const float* w    = (const float*)d_in[4];
    float* out  = (float*)d_out;
    float* diag = (float*)d_ws;   // S_SUP * N_NODES floats = 64 KB

    hipMemsetAsync(diag, 0, (size_t)S_SUP * N_NODES * sizeof(float), stream);

    {
        int total = S_SUP * E_EDGES;
        int block = 256;
        int grid  = (total + block - 1) / block;
        gc_edge_kernel<<<grid, block, 0, stream>>>(x, rows, cols, vals, diag);
    }
    {
        int total = N_NODES * D_OUT / 4;
        int block = 256;
        int grid  = (total + block - 1) / block;
        gc_out_kernel<<<grid, block, 0, stream>>>(diag, w, out);
    }
}